// Round 6
// baseline (503.377 us; speedup 1.0000x reference)
//
#include <hip/hip_runtime.h>
#include <math.h>

#define Bc 16
#define Nc 4096

typedef __attribute__((ext_vector_type(8))) short short8;
typedef __attribute__((ext_vector_type(4))) float floatx4;

__device__ __forceinline__ unsigned short f2bf(float f) {
    union { float f; unsigned int u; } v; v.f = f;
    unsigned int u = v.u;
    return (unsigned short)((u + 0x7fffu + ((u >> 16) & 1u)) >> 16);
}
__device__ __forceinline__ float bf2f(unsigned short u) {
    union { unsigned int u; float f; } v; v.u = ((unsigned int)u) << 16;
    return v.f;
}

// branch-free gelu: erf via Abramowitz-Stegun 7.1.26 (|err|<=1.5e-7)
// validated rounds 2-5: absmax identical to libm erff path
__device__ __forceinline__ float gelu_f(float x) {
    const float z = x * 0.70710678118654752f;
    const float az = fabsf(z);
    const float t = 1.f / (1.f + 0.3275911f * az);
    const float poly = t * (0.254829592f + t * (-0.284496736f +
                       t * (1.421413741f + t * (-1.453152027f + t * 1.061405429f))));
    const float e = __expf(-z * z);
    const float er = copysignf(1.f - poly * e, z);
    return 0.5f * x * (1.f + er);
}

// async global->LDS 16B/lane; LDS dest must be wave-uniform base + lane*16
__device__ __forceinline__ void gll16(const unsigned short* g, unsigned short* l) {
    __builtin_amdgcn_global_load_lds(
        (const __attribute__((address_space(1))) void*)g,
        (__attribute__((address_space(3))) void*)l,
        16, 0, 0);
}

// ---------------------------------------------------------------------------
// Swapped-operand bf16 GEMM, 512 threads, tile 128(M)x256(N), BK=64.
// Single-buffered LDS (48KB -> 2 blocks/CU; cross-block wave overlap hides
// barrier drains per m114). K fully unrolled (template) so reg-staged EPIs
// use a 2-deep register lookahead with compile-time indices (rule #20):
// loads for step t+2 issue at step t -> HBM latency hides under 2 K-steps.
// XOR-granule LDS swizzle (bank-conflict-free, gll16-compatible).
// EPI 1: + column sum-of-squares -> norm2        (G2)
// EPI 3: A reg-pipelined with LN+gelu_f (rowstats); + bf16 resid, fp32 (G5)
// EPI 5: pair-interleaved [s;v] weights + in-lane rope epilogue        (G1)
// EPI 6: A = [x (gll16) | w*(-Pi*attn) reg-pipelined], rowstats epi    (G34)
// ---------------------------------------------------------------------------
template <int EPI, int KT, int K0T, typename TOUT>
__global__ __launch_bounds__(512, 4) void gemm_bf(
    const unsigned short* __restrict__ A0, int lda0,
    const unsigned short* __restrict__ A1, int lda1,
    const unsigned short* __restrict__ W,
    const float* __restrict__ bias,
    const unsigned short* __restrict__ resid_bf,   // EPI3
    const float* __restrict__ Pi,                  // EPI6
    const float* __restrict__ Sb,                  // EPI6
    const float* __restrict__ Tb,                  // EPI6
    float* __restrict__ norm2,                     // EPI1
    float* __restrict__ rowstats,                  // EPI6 (write), EPI3 (read)
    const float* __restrict__ enc,                 // EPI5
    const float* __restrict__ lng,                 // EPI3
    const float* __restrict__ lnb,                 // EPI3
    TOUT* __restrict__ C, int N)
{
    constexpr int NT = KT / 64;
    constexpr bool REG = (EPI == 3) || (EPI == 6);
    __shared__ alignas(16) unsigned short As[128 * 64];
    __shared__ alignas(16) unsigned short Bs[256 * 64];

    const int t = threadIdx.x;
    const int bn = blockIdx.x, bm = blockIdx.y;
    const int lane = t & 63, wave = t >> 6;          // 8 waves
    const int wm = wave >> 2, wn = wave & 3;         // 2 x 4
    const int quad = lane >> 4, l16 = lane & 15;
    const int rt = t >> 3, st = t & 7;               // rt 0..63

    const int colin = (st ^ (rt & 7)) * 8;           // same for rows rt, rt+64
    const size_t g0 = (size_t)bm * 128 + rt;
    const size_t g1 = g0 + 64;

    float mean0 = 0.f, rstd0 = 0.f, mean1 = 0.f, rstd1 = 0.f;
    if constexpr (EPI == 3) {
        const float2 s0 = *(const float2*)(rowstats + g0 * 2);
        const float2 s1 = *(const float2*)(rowstats + g1 * 2);
        mean0 = s0.x * (1.f / 512.f);
        rstd0 = rsqrtf(s0.y * (1.f / 512.f) - mean0 * mean0 + 1e-5f);
        mean1 = s1.x * (1.f / 512.f);
        rstd1 = rsqrtf(s1.y * (1.f / 512.f) - mean1 * mean1 + 1e-5f);
    }

    float sc[2][4];
    if constexpr (EPI == 6) {
        const int b = (bm * 128) >> 12;              // uniform per block
        const floatx4 Sv = *(const floatx4*)(Sb + b * 4);
        const floatx4 Tv = *(const floatx4*)(Tb + b * 4);
        const floatx4 p0 = *(const floatx4*)(Pi + g0 * 4);
        const floatx4 p1 = *(const floatx4*)(Pi + g1 * 4);
        #pragma unroll
        for (int h = 0; h < 4; ++h) {
            const float at = 1.f / (1.f + Tv[h] / (Sv[h] + 1e-8f));
            sc[0][h] = -p0[h] * at;
            sc[1][h] = -p1[h] * at;
        }
    }

    short8 pa[2][2];
    auto loadA = [&](int tt, int slot) {
        const int cc = tt * 64 + colin;
        if constexpr (EPI == 6) {
            pa[slot][0] = *(const short8*)(A1 + g0 * (size_t)lda1 + (cc - K0T));
            pa[slot][1] = *(const short8*)(A1 + g1 * (size_t)lda1 + (cc - K0T));
        } else {
            pa[slot][0] = *(const short8*)(A0 + g0 * (size_t)lda0 + cc);
            pa[slot][1] = *(const short8*)(A0 + g1 * (size_t)lda0 + cc);
        }
    };
    auto xform = [&](int tt, int slot) {
        #pragma unroll
        for (int hh = 0; hh < 2; ++hh) {
            unsigned short* ldsa = As + (hh * 64 + rt) * 64 + st * 8;
            const short8 a = pa[slot][hh];
            short8 o;
            if constexpr (EPI == 6) {
                const float s = sc[hh][tt - K0T / 64];
                #pragma unroll
                for (int j = 0; j < 8; ++j) o[j] = (short)f2bf(bf2f((unsigned short)a[j]) * s);
            } else {  // EPI 3: LN(512)+gelu
                const float mu = hh ? mean1 : mean0;
                const float rs_ = hh ? rstd1 : rstd0;
                const int cc = tt * 64 + colin;
                const float4 ga = *(const float4*)(lng + cc);
                const float4 gb = *(const float4*)(lng + cc + 4);
                const float4 ba = *(const float4*)(lnb + cc);
                const float4 bb = *(const float4*)(lnb + cc + 4);
                const float vg[8] = {ga.x, ga.y, ga.z, ga.w, gb.x, gb.y, gb.z, gb.w};
                const float vb[8] = {ba.x, ba.y, ba.z, ba.w, bb.x, bb.y, bb.z, bb.w};
                #pragma unroll
                for (int j = 0; j < 8; ++j) {
                    const float ln = (bf2f((unsigned short)a[j]) - mu) * rs_ * vg[j] + vb[j];
                    o[j] = (short)f2bf(gelu_f(ln));
                }
            }
            *(short8*)ldsa = o;
        }
    };

    floatx4 acc[4][4];
    #pragma unroll
    for (int i = 0; i < 4; ++i)
        #pragma unroll
        for (int j = 0; j < 4; ++j)
            acc[i][j] = (floatx4){0.f, 0.f, 0.f, 0.f};

    if constexpr (EPI == 3) { loadA(0, 0); loadA(1, 1); }

    #pragma unroll
    for (int tt = 0; tt < NT; ++tt) {
        const int k0 = tt * 64;
        // ---- A staging ----
        if constexpr (EPI == 6) {
            if (k0 < K0T) {
                gll16(A0 + g0 * (size_t)lda0 + k0 + colin, As + rt * 64 + st * 8);
                gll16(A0 + g1 * (size_t)lda0 + k0 + colin, As + (64 + rt) * 64 + st * 8);
            } else {
                xform(tt, tt & 1);
            }
        } else if constexpr (EPI == 3) {
            xform(tt, tt & 1);
        } else {
            const unsigned short* s0 = (k0 < K0T)
                ? (A0 + g0 * (size_t)lda0 + k0 + colin)
                : (A1 + g0 * (size_t)lda1 + (k0 - K0T) + colin);
            const unsigned short* s1 = (k0 < K0T)
                ? (A0 + g1 * (size_t)lda0 + k0 + colin)
                : (A1 + g1 * (size_t)lda1 + (k0 - K0T) + colin);
            gll16(s0, As + rt * 64 + st * 8);
            gll16(s1, As + (64 + rt) * 64 + st * 8);
        }
        // ---- W staging: 256 rows x 64 ----
        #pragma unroll
        for (int hh = 0; hh < 4; ++hh)
            gll16(W + ((size_t)bn * 256 + hh * 64 + rt) * KT + k0 + colin,
                  Bs + (hh * 64 + rt) * 64 + st * 8);
        // ---- lookahead reg loads (2 steps ahead) ----
        if constexpr (EPI == 3) {
            if (tt + 2 < NT) loadA(tt + 2, tt & 1);
        }
        if constexpr (EPI == 6) {
            if (tt + 2 < NT && (tt + 2) * 64 >= K0T) loadA(tt + 2, tt & 1);
        }
        __syncthreads();
        #pragma unroll
        for (int kk = 0; kk < 2; ++kk) {
            short8 af[4], wf[4];
            #pragma unroll
            for (int i = 0; i < 4; ++i) {
                const int ra = wm * 64 + i * 16 + l16;
                af[i] = *(const short8*)(As + ra * 64 + ((quad + kk * 4) ^ (ra & 7)) * 8);
                const int rw = wn * 64 + i * 16 + l16;
                wf[i] = *(const short8*)(Bs + rw * 64 + ((quad + kk * 4) ^ (rw & 7)) * 8);
            }
            #pragma unroll
            for (int mi = 0; mi < 4; ++mi)
                #pragma unroll
                for (int ni = 0; ni < 4; ++ni)
                    acc[mi][ni] = __builtin_amdgcn_mfma_f32_16x16x32_bf16(
                        wf[ni], af[mi], acc[mi][ni], 0, 0, 0);
        }
        __syncthreads();
    }

    // epilogue: row = bm*128+wm*64+mi*16+l16; col = bn*256+wn*64+ni*16+quad*4+rg
    float rs[4], rq[4];
    if constexpr (EPI == 6) {
        #pragma unroll
        for (int m = 0; m < 4; ++m) { rs[m] = 0.f; rq[m] = 0.f; }
    }

    #pragma unroll
    for (int mi = 0; mi < 4; ++mi) {
        const size_t row = (size_t)bm * 128 + wm * 64 + mi * 16 + l16;
        #pragma unroll
        for (int ni = 0; ni < 4; ++ni) {
            const int cb = bn * 256 + wn * 64 + ni * 16 + quad * 4;
            const float4 b4 = *(const float4*)(bias + cb);
            if constexpr (EPI == 5) {
                // acc = {s_j, v_j, s_{j+1}, v_{j+1}}, j = cb/2 (even)
                const float s0 = acc[mi][ni][0] + b4.x;
                const float v0 = acc[mi][ni][1] + b4.y;
                const float s1 = acc[mi][ni][2] + b4.z;
                const float v1 = acc[mi][ni][3] + b4.w;
                const int j = cb >> 1;
                const int d = j & 63;
                const float2 e0 = *(const float2*)(enc + row * 64 + d);
                const float2 e1 = *(const float2*)(enc + 4194304 + row * 64 + d);
                const float r0 = s0 * e0.x - s1 * e1.x;
                const float r1 = s1 * e0.y + s0 * e1.y;
                ushort2 o;
                o.x = f2bf((r0 + v0) * (1.f / 3.f));
                o.y = f2bf((r1 + v1) * (1.f / 3.f));
                *(ushort2*)((unsigned short*)C + row * (size_t)N + j) = o;
            } else {
                float v[4] = {acc[mi][ni][0] + b4.x, acc[mi][ni][1] + b4.y,
                              acc[mi][ni][2] + b4.z, acc[mi][ni][3] + b4.w};
                if constexpr (EPI == 3) {
                    const ushort4 xr = *(const ushort4*)(resid_bf + row * (size_t)N + cb);
                    v[0] += bf2f(xr.x); v[1] += bf2f(xr.y);
                    v[2] += bf2f(xr.z); v[3] += bf2f(xr.w);
                }
                if constexpr (EPI == 6) {
                    #pragma unroll
                    for (int rg = 0; rg < 4; ++rg) { rs[mi] += v[rg]; rq[mi] += v[rg] * v[rg]; }
                }
                if constexpr (EPI == 1) {
                    float cs[4];
                    #pragma unroll
                    for (int rg = 0; rg < 4; ++rg) cs[rg] = v[rg] * v[rg];
                    #pragma unroll
                    for (int rg = 0; rg < 4; ++rg) {
                        float s = cs[rg];
                        s += __shfl_xor(s, 1, 64);
                        s += __shfl_xor(s, 2, 64);
                        s += __shfl_xor(s, 4, 64);
                        s += __shfl_xor(s, 8, 64);
                        if (l16 == 0) atomicAdd(&norm2[(bm >> 5) * 256 + cb + rg], s);
                    }
                }
                if constexpr (__is_same(TOUT, float)) {
                    float4 o; o.x = v[0]; o.y = v[1]; o.z = v[2]; o.w = v[3];
                    *(float4*)(C + row * (size_t)N + cb) = o;
                } else {
                    ushort4 o;
                    o.x = f2bf(v[0]); o.y = f2bf(v[1]); o.z = f2bf(v[2]); o.w = f2bf(v[3]);
                    *(ushort4*)(C + row * (size_t)N + cb) = o;
                }
            }
        }
    }
    if constexpr (EPI == 6) {
        #pragma unroll
        for (int mi = 0; mi < 4; ++mi) {
            float s = rs[mi], q = rq[mi];
            s += __shfl_xor(s, 16, 64); s += __shfl_xor(s, 32, 64);
            q += __shfl_xor(q, 16, 64); q += __shfl_xor(q, 32, 64);
            if (quad == 0) {
                const size_t row = (size_t)bm * 128 + wm * 64 + mi * 16 + l16;
                atomicAdd(&rowstats[row * 2], s);
                atomicAdd(&rowstats[row * 2 + 1], q);
            }
        }
    }
}

// ---------------------------------------------------------------------------
// single prep kernel: converts + fused weights + zeroing
// ---------------------------------------------------------------------------
__device__ __forceinline__ void conv8(const float* src, unsigned short* dst, int i) {
    const float4 f0 = *(const float4*)(src + (size_t)i * 8);
    const float4 f1 = *(const float4*)(src + (size_t)i * 8 + 4);
    short8 sv;
    sv[0] = (short)f2bf(f0.x); sv[1] = (short)f2bf(f0.y);
    sv[2] = (short)f2bf(f0.z); sv[3] = (short)f2bf(f0.w);
    sv[4] = (short)f2bf(f1.x); sv[5] = (short)f2bf(f1.y);
    sv[6] = (short)f2bf(f1.z); sv[7] = (short)f2bf(f1.w);
    *(short8*)(dst + (size_t)i * 8) = sv;
}

__global__ __launch_bounds__(256) void prep_all(
    const float* __restrict__ x, const float* __restrict__ Wqkv,
    const float* __restrict__ bqkv, const float* __restrict__ tssa_w,
    const float* __restrict__ op_w, const float* __restrict__ to_w,
    const float* __restrict__ to_b, const float* __restrict__ op_b,
    const float* __restrict__ f1w, const float* __restrict__ f2w,
    unsigned short* __restrict__ x_bf, unsigned short* __restrict__ Wsv,
    float* __restrict__ bsv, unsigned short* __restrict__ tssa_bf,
    unsigned short* __restrict__ Wf, float* __restrict__ bfb,
    unsigned short* __restrict__ ffn1_bf, unsigned short* __restrict__ ffn2_bf,
    float* __restrict__ zbase, float* __restrict__ rowstats)
{
    const int blk = blockIdx.x, tt = threadIdx.x;
    if (blk < 8192) {
        conv8(x, x_bf, blk * 256 + tt);
    } else if (blk < 8704) {
        // pair-interleaved: W'[2j] = Wq+Wk for out col j, W'[2j+1] = Wv
        const int r = blk - 8192, c = tt;      // r 0..511
        const int j = r >> 1;                  // out col 0..255
        const int h = j >> 6, dd = j & 63;
        const int base = h * 192 + dd * 3;
        if (!(r & 1)) {
            Wsv[r * 256 + c] = f2bf(Wqkv[(base + 0) * 256 + c] + Wqkv[(base + 1) * 256 + c]);
            if (c == 0) bsv[r] = bqkv[base] + bqkv[base + 1];
        } else {
            Wsv[r * 256 + c] = f2bf(Wqkv[(base + 2) * 256 + c]);
            if (c == 0) bsv[r] = bqkv[base + 2];
        }
    } else if (blk < 8960) {
        const int i = blk - 8704;
        float s = 0.f;
        for (int k = 0; k < 256; ++k) s += op_w[i * 256 + k] * to_w[k * 256 + tt];
        Wf[i * 256 + tt] = f2bf(s);
    } else if (blk == 8960) {
        float s = op_b[tt];
        for (int k = 0; k < 256; ++k) s += op_w[tt * 256 + k] * to_b[k];
        bfb[tt] = s;
    } else if (blk < 8993) {
        conv8(tssa_w, tssa_bf, (blk - 8961) * 256 + tt);
    } else if (blk < 9121) {
        conv8(f1w, ffn1_bf, (blk - 8993) * 256 + tt);
    } else if (blk < 9185) {
        conv8(f2w, ffn2_bf, (blk - 9121) * 256 + tt);
    } else {
        const int i = (blk - 9185) * 256 + tt;
        if (i < 4288) zbase[i] = 0.f;
        else if (i < 135360) rowstats[i - 4288] = 0.f;
    }
}

// ---------------------------------------------------------------------------
// prep2: W2comb = F1b @ Wf into right half of ffn1_bf; cbias = f1b + F1b@bfb
// ---------------------------------------------------------------------------
__global__ __launch_bounds__(256) void prep2(
    const float* __restrict__ f1w,          // 512x512
    const float* __restrict__ f1b,          // 512
    const unsigned short* __restrict__ Wf,  // 256x256 bf16
    const float* __restrict__ bfb,          // 256
    unsigned short* __restrict__ ffn1_bf,   // 512x512 bf16
    float* __restrict__ cbias)              // 512
{
    const int j = blockIdx.x, k = threadIdx.x;
    float s = 0.f;
    for (int i = 0; i < 256; ++i)
        s += f1w[(size_t)j * 512 + 256 + i] * bf2f(Wf[i * 256 + k]);
    ffn1_bf[(size_t)j * 512 + 256 + k] = f2bf(s);
    if (k == 0) {
        float c = f1b[j];
        for (int i = 0; i < 256; ++i) c += f1w[(size_t)j * 512 + 256 + i] * bfb[i];
        cbias[j] = c;
    }
}

// ---------------------------------------------------------------------------
// per-row softmax over heads + S/T accumulation
// ---------------------------------------------------------------------------
__global__ __launch_bounds__(256) void pi_kernel(const unsigned short* __restrict__ w,
                                                 const float* __restrict__ norm2,
                                                 const float* __restrict__ temp,
                                                 float* __restrict__ Pi,
                                                 float* __restrict__ S,
                                                 float* __restrict__ T) {
    const int t = threadIdx.x;
    const int i = t & 15;
    const int lr = t >> 4;
    const size_t r = (size_t)blockIdx.x * 16 + lr;
    const int b = (int)(r >> 12);
    const unsigned short* wrow = w + r * 256;
    const float* n2row = norm2 + b * 256;
    float raw[4], nrm[4];
    #pragma unroll
    for (int h = 0; h < 4; ++h) {
        const ushort4 wv = *(const ushort4*)(wrow + h * 64 + i * 4);
        const float w0 = bf2f(wv.x), w1 = bf2f(wv.y), w2 = bf2f(wv.z), w3 = bf2f(wv.w);
        const float4 n2 = *(const float4*)(n2row + h * 64 + i * 4);
        const float s0 = w0 * w0, s1 = w1 * w1, s2 = w2 * w2, s3 = w3 * w3;
        raw[h] = s0 + s1 + s2 + s3;
        nrm[h] = s0 / fmaxf(n2.x, 1e-24f) + s1 / fmaxf(n2.y, 1e-24f)
               + s2 / fmaxf(n2.z, 1e-24f) + s3 / fmaxf(n2.w, 1e-24f);
    }
    #pragma unroll
    for (int off = 1; off < 16; off <<= 1) {
        #pragma unroll
        for (int h = 0; h < 4; ++h) {
            raw[h] += __shfl_xor(raw[h], off, 64);
            nrm[h] += __shfl_xor(nrm[h], off, 64);
        }
    }
    float sw[4], m = -1e30f;
    #pragma unroll
    for (int h = 0; h < 4; ++h) { sw[h] = nrm[h] * temp[h]; m = fmaxf(m, sw[h]); }
    float e[4], Z = 0.f;
    #pragma unroll
    for (int h = 0; h < 4; ++h) { e[h] = expf(sw[h] - m); Z += e[h]; }
    const float invZ = 1.f / Z;
    float pi[4];
    #pragma unroll
    for (int h = 0; h < 4; ++h) pi[h] = e[h] * invZ;
    if (i < 4) Pi[r * 4 + i] = pi[i];

    __shared__ float sS[16][4], sT[16][4];
    if (i == 0) {
        #pragma unroll
        for (int h = 0; h < 4; ++h) { sS[lr][h] = pi[h]; sT[lr][h] = pi[h] * raw[h]; }
    }
    __syncthreads();
    if (t < 4) {
        float as = 0.f, at = 0.f;
        for (int rr = 0; rr < 16; ++rr) { as += sS[rr][t]; at += sT[rr][t]; }
        atomicAdd(&S[b * 4 + t], as);
        atomicAdd(&T[b * 4 + t], at);
    }
}

// ---------------------------------------------------------------------------
extern "C" void kernel_launch(void* const* d_in, const int* in_sizes, int n_in,
                              void* d_out, int out_size, void* d_ws, size_t ws_size,
                              hipStream_t stream) {
    (void)in_sizes; (void)n_in; (void)out_size; (void)ws_size;
    const float* x          = (const float*)d_in[0];
    const float* enc        = (const float*)d_in[1];
    const float* Wqkv_w     = (const float*)d_in[2];
    const float* Wqkv_b     = (const float*)d_in[3];
    const float* tssa_qkv_w = (const float*)d_in[4];
    const float* tssa_qkv_b = (const float*)d_in[5];
    const float* temp       = (const float*)d_in[6];
    const float* tssa_out_w = (const float*)d_in[7];
    const float* tssa_out_b = (const float*)d_in[8];
    const float* out_proj_w = (const float*)d_in[9];
    const float* out_proj_b = (const float*)d_in[10];
    const float* ffn1_w     = (const float*)d_in[11];
    const float* ffn1_b     = (const float*)d_in[12];
    const float* ln_g       = (const float*)d_in[13];
    const float* ln_b       = (const float*)d_in[14];
    const float* ffn2_w     = (const float*)d_in[15];
    const float* ffn2_b     = (const float*)d_in[16];
    float* outp = (float*)d_out;

    const int M = Bc * Nc;  // 65536

    char* ws = (char*)d_ws;
    unsigned short* x_bf  = (unsigned short*)(ws);
    unsigned short* wi_bf = (unsigned short*)(ws + (size_t)(32 << 20));
    unsigned short* h1_bf = (unsigned short*)(ws + (size_t)(32 << 20));
    unsigned short* w_bf  = (unsigned short*)(ws + (size_t)(64 << 20));
    float* fb    = (float*)(ws + (size_t)(128 << 20));
    float* Pi    = fb;                 // 262144
    float* norm2 = Pi + 262144;        // 4096  <- zero base
    float* Sb    = norm2 + 4096;       // 64
    float* Tb    = Sb + 64;            // 64
    float* cbias = Tb + 64;            // 512
    float* bsv   = cbias + 512;        // 512
    float* bfb   = bsv + 512;          // 256
    float* rowstats = bfb + 256;       // 131072
    unsigned short* Wsv_bf  = (unsigned short*)(rowstats + 131072);
    unsigned short* tssa_bf = Wsv_bf + 131072;
    unsigned short* Wf_bf   = tssa_bf + 65536;
    unsigned short* ffn1_bf = Wf_bf + 65536;
    unsigned short* ffn2_bf = ffn1_bf + 262144;

    // 1. prep
    prep_all<<<9714, 256, 0, stream>>>(
        x, Wqkv_w, Wqkv_b, tssa_qkv_w, out_proj_w, tssa_out_w, tssa_out_b,
        out_proj_b, ffn1_w, ffn2_w,
        x_bf, Wsv_bf, bsv, tssa_bf, Wf_bf, bfb, ffn1_bf, ffn2_bf,
        norm2, rowstats);

    // 1b. prep2: fold Wf into ffn1 right half (eliminates old G3)
    prep2<<<512, 256, 0, stream>>>(ffn1_w, ffn1_b, Wf_bf, bfb, ffn1_bf, cbias);

    // 2. G1: wi = rope-combine(x_bf @ Wsv'^T + b), pair-interleaved weights
    gemm_bf<5, 256, 256, unsigned short><<<dim3(2, M / 128), 512, 0, stream>>>(
        x_bf, 256, x_bf, 256, Wsv_bf, bsv,
        nullptr, nullptr, nullptr, nullptr, nullptr, nullptr,
        enc, nullptr, nullptr, wi_bf, 256);

    // 3. G2: w = wi @ tssa^T + b -> bf16, fused colsq -> norm2
    gemm_bf<1, 256, 256, unsigned short><<<dim3(1, M / 128), 512, 0, stream>>>(
        wi_bf, 256, wi_bf, 256, tssa_bf, tssa_qkv_b,
        nullptr, nullptr, nullptr, nullptr, norm2, nullptr,
        nullptr, nullptr, nullptr, w_bf, 256);

    // 4. stats
    pi_kernel<<<4096, 256, 0, stream>>>(w_bf, norm2, temp, Pi, Sb, Tb);

    // 5. G34: h1 = [x | w*(-Pi*attn)] @ [F1a | F1b*Wf]^T + cbias,
    //    fused row sum/sumsq -> rowstats (attn = 1/(1+T/(S+eps)) inline)
    gemm_bf<6, 512, 256, unsigned short><<<dim3(2, M / 128), 512, 0, stream>>>(
        x_bf, 256, w_bf, 256, ffn1_bf, cbias,
        nullptr, Pi, Sb, Tb, nullptr, rowstats,
        nullptr, nullptr, nullptr, h1_bf, 512);

    // 6. G5: out = x + gelu_f(LN(h1)) @ ffn2^T + b (reg-pipelined A staging)
    gemm_bf<3, 512, 512, float><<<dim3(1, M / 128), 512, 0, stream>>>(
        h1_bf, 512, h1_bf, 512, ffn2_bf, ffn2_b,
        x_bf, nullptr, nullptr, nullptr, nullptr, rowstats,
        nullptr, ln_g, ln_b, outp, 256);
}

// Round 7
// 466.907 us; speedup vs baseline: 1.0781x; 1.0781x over previous
//
#include <hip/hip_runtime.h>
#include <math.h>

#define Bc 16
#define Nc 4096

typedef __attribute__((ext_vector_type(8))) short short8;
typedef __attribute__((ext_vector_type(4))) float floatx4;

__device__ __forceinline__ unsigned short f2bf(float f) {
    union { float f; unsigned int u; } v; v.f = f;
    unsigned int u = v.u;
    return (unsigned short)((u + 0x7fffu + ((u >> 16) & 1u)) >> 16);
}
__device__ __forceinline__ float bf2f(unsigned short u) {
    union { unsigned int u; float f; } v; v.u = ((unsigned int)u) << 16;
    return v.f;
}

// branch-free gelu: erf via Abramowitz-Stegun 7.1.26 (|err|<=1.5e-7)
// validated rounds 2-6: absmax identical to libm erff path
__device__ __forceinline__ float gelu_f(float x) {
    const float z = x * 0.70710678118654752f;
    const float az = fabsf(z);
    const float t = 1.f / (1.f + 0.3275911f * az);
    const float poly = t * (0.254829592f + t * (-0.284496736f +
                       t * (1.421413741f + t * (-1.453152027f + t * 1.061405429f))));
    const float e = __expf(-z * z);
    const float er = copysignf(1.f - poly * e, z);
    return 0.5f * x * (1.f + er);
}

// async global->LDS 16B/lane; LDS dest must be wave-uniform base + lane*16
__device__ __forceinline__ void gll16(const unsigned short* g, unsigned short* l) {
    __builtin_amdgcn_global_load_lds(
        (const __attribute__((address_space(1))) void*)g,
        (__attribute__((address_space(3))) void*)l,
        16, 0, 0);
}

// ---------------------------------------------------------------------------
// Swapped-operand bf16 GEMM, 512 threads, tile 128(M)x256(N), BK=64.
// Single-buffered LDS (48KB; round-2 dbuf, round-4 small-tile, round-5/6
// reg-pipelines all regressed -- this is the verified-best structure).
// XOR-granule LDS swizzle (bank-conflict-free, gll16-compatible).
// EPI 1: + column sum-of-squares -> norm2        (G2)
// EPI 2: A staged with scale -Pi*attn, attn computed inline from S,T (G3)
// EPI 3: A staged with LN+gelu_f (rowstats); + bf16 residual, fp32 out (G5)
// EPI 4: + per-row sum/sumsq -> rowstats         (G4)
// ---------------------------------------------------------------------------
template <int EPI, typename TOUT>
__global__ __launch_bounds__(512) void gemm_bf(
    const unsigned short* __restrict__ A0, int lda0,
    const unsigned short* __restrict__ A1, int lda1, int K0,
    const unsigned short* __restrict__ W,
    const float* __restrict__ bias,
    const unsigned short* __restrict__ resid_bf,   // EPI3
    const float* __restrict__ Pi,                  // EPI2
    const float* __restrict__ Sb,                  // EPI2
    const float* __restrict__ Tb,                  // EPI2
    float* __restrict__ norm2,                     // EPI1
    float* __restrict__ rowstats,                  // EPI4 (write), EPI3 (read)
    const float* __restrict__ lng,                 // EPI3
    const float* __restrict__ lnb,                 // EPI3
    TOUT* __restrict__ C, int N, int K)
{
    __shared__ alignas(16) unsigned short As[128 * 64];
    __shared__ alignas(16) unsigned short Bs[256 * 64];

    const int t = threadIdx.x;
    const int bn = blockIdx.x, bm = blockIdx.y;
    const int lane = t & 63, wave = t >> 6;          // 8 waves
    const int wm = wave >> 2, wn = wave & 3;         // 2 x 4
    const int quad = lane >> 4, l16 = lane & 15;
    const int rt = t >> 3, st = t & 7;               // rt 0..63

    float mean0 = 0.f, rstd0 = 0.f, mean1 = 0.f, rstd1 = 0.f;
    if constexpr (EPI == 3) {
        const size_t g0 = (size_t)bm * 128 + rt;
        const float2 s0 = *(const float2*)(rowstats + g0 * 2);
        const float2 s1 = *(const float2*)(rowstats + (g0 + 64) * 2);
        mean0 = s0.x * (1.f / 512.f);
        rstd0 = rsqrtf(s0.y * (1.f / 512.f) - mean0 * mean0 + 1e-5f);
        mean1 = s1.x * (1.f / 512.f);
        rstd1 = rsqrtf(s1.y * (1.f / 512.f) - mean1 * mean1 + 1e-5f);
    }

    floatx4 acc[4][4];
    #pragma unroll
    for (int i = 0; i < 4; ++i)
        #pragma unroll
        for (int j = 0; j < 4; ++j)
            acc[i][j] = (floatx4){0.f, 0.f, 0.f, 0.f};

    for (int k0 = 0; k0 < K; k0 += 64) {
        // A tile: 128 rows x 64
        #pragma unroll
        for (int hh = 0; hh < 2; ++hh) {
            const int row = hh * 64 + rt;
            const int col = k0 + (st ^ (row & 7)) * 8;
            unsigned short* ldsa = As + row * 64 + st * 8;
            const size_t grow = (size_t)bm * 128 + row;
            if constexpr (EPI == 2) {
                const int b = (int)(grow >> 12);
                const int hd = col >> 6;
                const float Sv = Sb[b * 4 + hd], Tv = Tb[b * 4 + hd];
                const float at = 1.f / (1.f + Tv / (Sv + 1e-8f));
                const float sc = -Pi[grow * 4 + hd] * at;
                const short8 a = *(const short8*)(A0 + grow * (size_t)lda0 + col);
                short8 o;
                #pragma unroll
                for (int j = 0; j < 8; ++j) o[j] = (short)f2bf(bf2f((unsigned short)a[j]) * sc);
                *(short8*)ldsa = o;
            } else if constexpr (EPI == 3) {
                // fused LayerNorm(512) + gelu on the fly (stats precomputed)
                const float mean = hh ? mean1 : mean0;
                const float rstd = hh ? rstd1 : rstd0;
                const short8 a = *(const short8*)(A0 + grow * (size_t)lda0 + col);
                const float4 ga = *(const float4*)(lng + col);
                const float4 gb = *(const float4*)(lng + col + 4);
                const float4 ba = *(const float4*)(lnb + col);
                const float4 bb = *(const float4*)(lnb + col + 4);
                const float vg[8] = {ga.x, ga.y, ga.z, ga.w, gb.x, gb.y, gb.z, gb.w};
                const float vb[8] = {ba.x, ba.y, ba.z, ba.w, bb.x, bb.y, bb.z, bb.w};
                short8 o;
                #pragma unroll
                for (int jj = 0; jj < 8; ++jj) {
                    const float ln = (bf2f((unsigned short)a[jj]) - mean) * rstd * vg[jj] + vb[jj];
                    o[jj] = (short)f2bf(gelu_f(ln));
                }
                *(short8*)ldsa = o;
            } else {
                const unsigned short* src = (col < K0)
                    ? (A0 + grow * (size_t)lda0 + col)
                    : (A1 + grow * (size_t)lda1 + (col - K0));
                gll16(src, ldsa);
            }
        }
        // W tile: 256 rows x 64
        #pragma unroll
        for (int hh = 0; hh < 4; ++hh) {
            const int row = hh * 64 + rt;
            const int col = k0 + (st ^ (row & 7)) * 8;
            gll16(W + ((size_t)bn * 256 + row) * (size_t)K + col, Bs + row * 64 + st * 8);
        }
        __syncthreads();
        #pragma unroll
        for (int kk = 0; kk < 2; ++kk) {
            short8 af[4], wf[4];
            #pragma unroll
            for (int i = 0; i < 4; ++i) {
                const int ra = wm * 64 + i * 16 + l16;
                af[i] = *(const short8*)(As + ra * 64 + ((quad + kk * 4) ^ (ra & 7)) * 8);
                const int rw = wn * 64 + i * 16 + l16;
                wf[i] = *(const short8*)(Bs + rw * 64 + ((quad + kk * 4) ^ (rw & 7)) * 8);
            }
            #pragma unroll
            for (int mi = 0; mi < 4; ++mi)
                #pragma unroll
                for (int ni = 0; ni < 4; ++ni)
                    acc[mi][ni] = __builtin_amdgcn_mfma_f32_16x16x32_bf16(
                        wf[ni], af[mi], acc[mi][ni], 0, 0, 0);
        }
        __syncthreads();
    }

    // epilogue: row = bm*128+wm*64+mi*16+l16; col = bn*256+wn*64+ni*16+quad*4+rg
    float rs[4], rq[4];
    if constexpr (EPI == 4) {
        #pragma unroll
        for (int m = 0; m < 4; ++m) { rs[m] = 0.f; rq[m] = 0.f; }
    }

    #pragma unroll
    for (int mi = 0; mi < 4; ++mi) {
        const size_t row = (size_t)bm * 128 + wm * 64 + mi * 16 + l16;
        #pragma unroll
        for (int ni = 0; ni < 4; ++ni) {
            const int cb = bn * 256 + wn * 64 + ni * 16 + quad * 4;
            const float4 b4 = *(const float4*)(bias + cb);
            float v[4] = {acc[mi][ni][0] + b4.x, acc[mi][ni][1] + b4.y,
                          acc[mi][ni][2] + b4.z, acc[mi][ni][3] + b4.w};
            if constexpr (EPI == 3) {
                const ushort4 xr = *(const ushort4*)(resid_bf + row * (size_t)N + cb);
                v[0] += bf2f(xr.x); v[1] += bf2f(xr.y);
                v[2] += bf2f(xr.z); v[3] += bf2f(xr.w);
            }
            if constexpr (EPI == 4) {
                #pragma unroll
                for (int rg = 0; rg < 4; ++rg) { rs[mi] += v[rg]; rq[mi] += v[rg] * v[rg]; }
            }
            if constexpr (EPI == 1) {
                float cs[4];
                #pragma unroll
                for (int rg = 0; rg < 4; ++rg) cs[rg] = v[rg] * v[rg];
                #pragma unroll
                for (int rg = 0; rg < 4; ++rg) {
                    float s = cs[rg];
                    s += __shfl_xor(s, 1, 64);
                    s += __shfl_xor(s, 2, 64);
                    s += __shfl_xor(s, 4, 64);
                    s += __shfl_xor(s, 8, 64);
                    if (l16 == 0) atomicAdd(&norm2[(bm >> 5) * 256 + cb + rg], s);
                }
            }
            if constexpr (__is_same(TOUT, float)) {
                float4 o; o.x = v[0]; o.y = v[1]; o.z = v[2]; o.w = v[3];
                *(float4*)(C + row * (size_t)N + cb) = o;
            } else {
                ushort4 o;
                o.x = f2bf(v[0]); o.y = f2bf(v[1]); o.z = f2bf(v[2]); o.w = f2bf(v[3]);
                *(ushort4*)(C + row * (size_t)N + cb) = o;
            }
        }
    }
    if constexpr (EPI == 4) {
        #pragma unroll
        for (int mi = 0; mi < 4; ++mi) {
            float s = rs[mi], q = rq[mi];
            s += __shfl_xor(s, 16, 64); s += __shfl_xor(s, 32, 64);
            q += __shfl_xor(q, 16, 64); q += __shfl_xor(q, 32, 64);
            if (quad == 0) {
                const size_t row = (size_t)bm * 128 + wm * 64 + mi * 16 + l16;
                atomicAdd(&rowstats[row * 2], s);
                atomicAdd(&rowstats[row * 2 + 1], q);
            }
        }
    }
}

// ---------------------------------------------------------------------------
// G1 (swapped, 256 threads, 128x128 tile, BK=64): dual-acc s/v GEMM with
// in-lane rope epilogue. wi = ((q+k)*e0 + rot(q+k)*e1 + v)/3.
// Round-0 verified at 67.9us -- measurably faster than the EPI5 shared-
// template variant (~+100us, isolated via the r0<->r3 component ledger).
// ---------------------------------------------------------------------------
__global__ __launch_bounds__(256) void gemm_rope(
    const unsigned short* __restrict__ A,    // x_bf
    const unsigned short* __restrict__ Wsv,  // 512x256: rows 0-255 s, 256-511 v
    const float* __restrict__ bsv,           // 512
    const float* __restrict__ enc,
    unsigned short* __restrict__ wi)
{
    __shared__ alignas(16) unsigned short As[128 * 64];
    __shared__ alignas(16) unsigned short Ss[128 * 64];
    __shared__ alignas(16) unsigned short Vs[128 * 64];

    const int t = threadIdx.x;
    const int bn = blockIdx.x, bm = blockIdx.y;
    const int lane = t & 63, wave = t >> 6;
    const int wm = wave >> 1, wn = wave & 1;
    const int quad = lane >> 4, l16 = lane & 15;
    const int rt = t >> 3, st = t & 7;   // rt 0..31

    floatx4 accs[4][4], accv[4][4];
    #pragma unroll
    for (int i = 0; i < 4; ++i)
        #pragma unroll
        for (int j = 0; j < 4; ++j) {
            accs[i][j] = (floatx4){0.f, 0.f, 0.f, 0.f};
            accv[i][j] = (floatx4){0.f, 0.f, 0.f, 0.f};
        }

    for (int k0 = 0; k0 < 256; k0 += 64) {
        #pragma unroll
        for (int hh = 0; hh < 4; ++hh) {
            const int row = hh * 32 + rt;
            const int col = k0 + (st ^ (row & 7)) * 8;
            gll16(A + ((size_t)bm * 128 + row) * 256 + col, As + row * 64 + st * 8);
            gll16(Wsv + (size_t)(bn * 128 + row) * 256 + col, Ss + row * 64 + st * 8);
            gll16(Wsv + (size_t)(256 + bn * 128 + row) * 256 + col, Vs + row * 64 + st * 8);
        }
        __syncthreads();
        #pragma unroll
        for (int kk = 0; kk < 2; ++kk) {
            short8 af[4], sf[4], vf[4];
            #pragma unroll
            for (int i = 0; i < 4; ++i) {
                const int ra = wm * 64 + i * 16 + l16;
                af[i] = *(const short8*)(As + ra * 64 + ((quad + kk * 4) ^ (ra & 7)) * 8);
                const int rw = wn * 64 + i * 16 + l16;
                sf[i] = *(const short8*)(Ss + rw * 64 + ((quad + kk * 4) ^ (rw & 7)) * 8);
                vf[i] = *(const short8*)(Vs + rw * 64 + ((quad + kk * 4) ^ (rw & 7)) * 8);
            }
            #pragma unroll
            for (int mi = 0; mi < 4; ++mi)
                #pragma unroll
                for (int ni = 0; ni < 4; ++ni) {
                    accs[mi][ni] = __builtin_amdgcn_mfma_f32_16x16x32_bf16(sf[ni], af[mi], accs[mi][ni], 0, 0, 0);
                    accv[mi][ni] = __builtin_amdgcn_mfma_f32_16x16x32_bf16(vf[ni], af[mi], accv[mi][ni], 0, 0, 0);
                }
        }
        __syncthreads();
    }

    // epilogue: row = bm*128+wm*64+mi*16+l16; cols cb..cb+3 (pairs in-lane)
    #pragma unroll
    for (int mi = 0; mi < 4; ++mi) {
        const size_t row = (size_t)bm * 128 + wm * 64 + mi * 16 + l16;
        #pragma unroll
        for (int ni = 0; ni < 4; ++ni) {
            const int cb = bn * 128 + wn * 64 + ni * 16 + quad * 4;
            const int d = cb & 63;
            const float s0 = accs[mi][ni][0] + bsv[cb];
            const float s1 = accs[mi][ni][1] + bsv[cb + 1];
            const float s2 = accs[mi][ni][2] + bsv[cb + 2];
            const float s3 = accs[mi][ni][3] + bsv[cb + 3];
            const float v0 = accv[mi][ni][0] + bsv[256 + cb];
            const float v1 = accv[mi][ni][1] + bsv[256 + cb + 1];
            const float v2 = accv[mi][ni][2] + bsv[256 + cb + 2];
            const float v3 = accv[mi][ni][3] + bsv[256 + cb + 3];
            const float4 e0q = *(const float4*)(enc + row * 64 + d);
            const float4 e1q = *(const float4*)(enc + 4194304 + row * 64 + d);
            const float r0 = s0 * e0q.x - s1 * e1q.x;
            const float r1 = s1 * e0q.y + s0 * e1q.y;
            const float r2 = s2 * e0q.z - s3 * e1q.z;
            const float r3 = s3 * e0q.w + s2 * e1q.w;
            ushort4 o;
            o.x = f2bf((r0 + v0) * (1.f / 3.f));
            o.y = f2bf((r1 + v1) * (1.f / 3.f));
            o.z = f2bf((r2 + v2) * (1.f / 3.f));
            o.w = f2bf((r3 + v3) * (1.f / 3.f));
            *(ushort4*)(wi + row * 256 + cb) = o;
        }
    }
}

// ---------------------------------------------------------------------------
// single prep kernel: converts + fused weights + zeroing
// ---------------------------------------------------------------------------
__device__ __forceinline__ void conv8(const float* src, unsigned short* dst, int i) {
    const float4 f0 = *(const float4*)(src + (size_t)i * 8);
    const float4 f1 = *(const float4*)(src + (size_t)i * 8 + 4);
    short8 sv;
    sv[0] = (short)f2bf(f0.x); sv[1] = (short)f2bf(f0.y);
    sv[2] = (short)f2bf(f0.z); sv[3] = (short)f2bf(f0.w);
    sv[4] = (short)f2bf(f1.x); sv[5] = (short)f2bf(f1.y);
    sv[6] = (short)f2bf(f1.z); sv[7] = (short)f2bf(f1.w);
    *(short8*)(dst + (size_t)i * 8) = sv;
}

__global__ __launch_bounds__(256) void prep_all(
    const float* __restrict__ x, const float* __restrict__ Wqkv,
    const float* __restrict__ bqkv, const float* __restrict__ tssa_w,
    const float* __restrict__ op_w, const float* __restrict__ to_w,
    const float* __restrict__ to_b, const float* __restrict__ op_b,
    const float* __restrict__ f1w, const float* __restrict__ f2w,
    unsigned short* __restrict__ x_bf, unsigned short* __restrict__ Wsv,
    float* __restrict__ bsv, unsigned short* __restrict__ tssa_bf,
    unsigned short* __restrict__ Wf, float* __restrict__ bfb,
    unsigned short* __restrict__ ffn1_bf, unsigned short* __restrict__ ffn2_bf,
    float* __restrict__ zbase, float* __restrict__ rowstats)
{
    const int blk = blockIdx.x, tt = threadIdx.x;
    if (blk < 8192) {
        conv8(x, x_bf, blk * 256 + tt);
    } else if (blk < 8704) {
        const int r = blk - 8192, c = tt;
        const int cd = r & 255;
        const int h = cd >> 6, dd = cd & 63;
        const int base = h * 192 + dd * 3;
        if (r < 256) {
            Wsv[r * 256 + c] = f2bf(Wqkv[(base + 0) * 256 + c] + Wqkv[(base + 1) * 256 + c]);
            if (c == 0) bsv[r] = bqkv[base] + bqkv[base + 1];
        } else {
            Wsv[r * 256 + c] = f2bf(Wqkv[(base + 2) * 256 + c]);
            if (c == 0) bsv[r] = bqkv[base + 2];
        }
    } else if (blk < 8960) {
        const int i = blk - 8704;
        float s = 0.f;
        for (int k = 0; k < 256; ++k) s += op_w[i * 256 + k] * to_w[k * 256 + tt];
        Wf[i * 256 + tt] = f2bf(s);
    } else if (blk == 8960) {
        float s = op_b[tt];
        for (int k = 0; k < 256; ++k) s += op_w[tt * 256 + k] * to_b[k];
        bfb[tt] = s;
    } else if (blk < 8993) {
        conv8(tssa_w, tssa_bf, (blk - 8961) * 256 + tt);
    } else if (blk < 9121) {
        conv8(f1w, ffn1_bf, (blk - 8993) * 256 + tt);
    } else if (blk < 9185) {
        conv8(f2w, ffn2_bf, (blk - 9121) * 256 + tt);
    } else {
        const int i = (blk - 9185) * 256 + tt;
        if (i < 4288) zbase[i] = 0.f;
        else if (i < 135360) rowstats[i - 4288] = 0.f;
    }
}

// ---------------------------------------------------------------------------
// per-row softmax over heads + S/T accumulation
// ---------------------------------------------------------------------------
__global__ __launch_bounds__(256) void pi_kernel(const unsigned short* __restrict__ w,
                                                 const float* __restrict__ norm2,
                                                 const float* __restrict__ temp,
                                                 float* __restrict__ Pi,
                                                 float* __restrict__ S,
                                                 float* __restrict__ T) {
    const int t = threadIdx.x;
    const int i = t & 15;
    const int lr = t >> 4;
    const size_t r = (size_t)blockIdx.x * 16 + lr;
    const int b = (int)(r >> 12);
    const unsigned short* wrow = w + r * 256;
    const float* n2row = norm2 + b * 256;
    float raw[4], nrm[4];
    #pragma unroll
    for (int h = 0; h < 4; ++h) {
        const ushort4 wv = *(const ushort4*)(wrow + h * 64 + i * 4);
        const float w0 = bf2f(wv.x), w1 = bf2f(wv.y), w2 = bf2f(wv.z), w3 = bf2f(wv.w);
        const float4 n2 = *(const float4*)(n2row + h * 64 + i * 4);
        const float s0 = w0 * w0, s1 = w1 * w1, s2 = w2 * w2, s3 = w3 * w3;
        raw[h] = s0 + s1 + s2 + s3;
        nrm[h] = s0 / fmaxf(n2.x, 1e-24f) + s1 / fmaxf(n2.y, 1e-24f)
               + s2 / fmaxf(n2.z, 1e-24f) + s3 / fmaxf(n2.w, 1e-24f);
    }
    #pragma unroll
    for (int off = 1; off < 16; off <<= 1) {
        #pragma unroll
        for (int h = 0; h < 4; ++h) {
            raw[h] += __shfl_xor(raw[h], off, 64);
            nrm[h] += __shfl_xor(nrm[h], off, 64);
        }
    }
    float sw[4], m = -1e30f;
    #pragma unroll
    for (int h = 0; h < 4; ++h) { sw[h] = nrm[h] * temp[h]; m = fmaxf(m, sw[h]); }
    float e[4], Z = 0.f;
    #pragma unroll
    for (int h = 0; h < 4; ++h) { e[h] = expf(sw[h] - m); Z += e[h]; }
    const float invZ = 1.f / Z;
    float pi[4];
    #pragma unroll
    for (int h = 0; h < 4; ++h) pi[h] = e[h] * invZ;
    if (i < 4) Pi[r * 4 + i] = pi[i];

    __shared__ float sS[16][4], sT[16][4];
    if (i == 0) {
        #pragma unroll
        for (int h = 0; h < 4; ++h) { sS[lr][h] = pi[h]; sT[lr][h] = pi[h] * raw[h]; }
    }
    __syncthreads();
    if (t < 4) {
        float as = 0.f, at = 0.f;
        for (int rr = 0; rr < 16; ++rr) { as += sS[rr][t]; at += sT[rr][t]; }
        atomicAdd(&S[b * 4 + t], as);
        atomicAdd(&T[b * 4 + t], at);
    }
}

// ---------------------------------------------------------------------------
extern "C" void kernel_launch(void* const* d_in, const int* in_sizes, int n_in,
                              void* d_out, int out_size, void* d_ws, size_t ws_size,
                              hipStream_t stream) {
    (void)in_sizes; (void)n_in; (void)out_size; (void)ws_size;
    const float* x          = (const float*)d_in[0];
    const float* enc        = (const float*)d_in[1];
    const float* Wqkv_w     = (const float*)d_in[2];
    const float* Wqkv_b     = (const float*)d_in[3];
    const float* tssa_qkv_w = (const float*)d_in[4];
    const float* tssa_qkv_b = (const float*)d_in[5];
    const float* temp       = (const float*)d_in[6];
    const float* tssa_out_w = (const float*)d_in[7];
    const float* tssa_out_b = (const float*)d_in[8];
    const float* out_proj_w = (const float*)d_in[9];
    const float* out_proj_b = (const float*)d_in[10];
    const float* ffn1_w     = (const float*)d_in[11];
    const float* ffn1_b     = (const float*)d_in[12];
    const float* ln_g       = (const float*)d_in[13];
    const float* ln_b       = (const float*)d_in[14];
    const float* ffn2_w     = (const float*)d_in[15];
    const float* ffn2_b     = (const float*)d_in[16];
    float* outp = (float*)d_out;

    const int M = Bc * Nc;  // 65536

    char* ws = (char*)d_ws;
    unsigned short* x_bf  = (unsigned short*)(ws);
    unsigned short* wi_bf = (unsigned short*)(ws + (size_t)(32 << 20));
    unsigned short* h1_bf = (unsigned short*)(ws + (size_t)(32 << 20));
    unsigned short* w_bf  = (unsigned short*)(ws + (size_t)(64 << 20));
    unsigned short* msg_bf= (unsigned short*)(ws + (size_t)(96 << 20));
    float* fb    = (float*)(ws + (size_t)(128 << 20));
    float* Pi    = fb;                 // 262144
    float* norm2 = Pi + 262144;        // 4096  <- zero base
    float* Sb    = norm2 + 4096;       // 64
    float* Tb    = Sb + 64;            // 64
    float* attnb = Tb + 64;            // 64 (unused, kept for zero-range layout)
    float* bsv   = attnb + 64;         // 512
    float* bfb   = bsv + 512;          // 256
    float* rowstats = bfb + 256;       // 131072
    unsigned short* Wsv_bf  = (unsigned short*)(rowstats + 131072);
    unsigned short* tssa_bf = Wsv_bf + 131072;
    unsigned short* Wf_bf   = tssa_bf + 65536;
    unsigned short* ffn1_bf = Wf_bf + 65536;
    unsigned short* ffn2_bf = ffn1_bf + 262144;

    // 1. prep
    prep_all<<<9714, 256, 0, stream>>>(
        x, Wqkv_w, Wqkv_b, tssa_qkv_w, out_proj_w, tssa_out_w, tssa_out_b,
        out_proj_b, ffn1_w, ffn2_w,
        x_bf, Wsv_bf, bsv, tssa_bf, Wf_bf, bfb, ffn1_bf, ffn2_bf,
        norm2, rowstats);

    // 2. G1: wi = rope-combine(x_bf @ [Wqk;Wv]^T + b)  (round-0 gemm_rope)
    gemm_rope<<<dim3(2, M / 128), 256, 0, stream>>>(x_bf, Wsv_bf, bsv, enc, wi_bf);

    // 3. G2: w = wi @ tssa^T + b -> bf16, fused colsq -> norm2
    gemm_bf<1, unsigned short><<<dim3(1, M / 128), 512, 0, stream>>>(
        wi_bf, 256, wi_bf, 256, 256, tssa_bf, tssa_qkv_b,
        nullptr, nullptr, nullptr, nullptr, norm2, nullptr,
        nullptr, nullptr, w_bf, 256, 256);

    // 4. stats (attn folded into G3's staging)
    pi_kernel<<<4096, 256, 0, stream>>>(w_bf, norm2, temp, Pi, Sb, Tb);

    // 5. G3: message = (-w*Pi*attn) @ Wf^T + bfb, attn = 1/(1+T/(S+eps)) inline
    gemm_bf<2, unsigned short><<<dim3(1, M / 128), 512, 0, stream>>>(
        w_bf, 256, w_bf, 256, 256, Wf_bf, bfb,
        nullptr, Pi, Sb, Tb, nullptr, nullptr,
        nullptr, nullptr, msg_bf, 256, 256);

    // 6. G4: h1 = [x_bf, msg] @ ffn1^T + b -> bf16, fused row sum/sumsq
    gemm_bf<4, unsigned short><<<dim3(2, M / 128), 512, 0, stream>>>(
        x_bf, 256, msg_bf, 256, 256, ffn1_bf, ffn1_b,
        nullptr, nullptr, nullptr, nullptr, nullptr, rowstats,
        nullptr, nullptr, h1_bf, 512, 512);

    // 7. G5: out = x + gelu_f(LN(h1)) @ ffn2^T + b (LN+gelu fused in staging)
    gemm_bf<3, float><<<dim3(1, M / 128), 512, 0, stream>>>(
        h1_bf, 512, h1_bf, 512, 512, ffn2_bf, ffn2_b,
        x_bf, nullptr, nullptr, nullptr, nullptr, rowstats,
        ln_g, ln_b, outp, 256, 512);
}

// Round 8
// 451.586 us; speedup vs baseline: 1.1147x; 1.0339x over previous
//
#include <hip/hip_runtime.h>
#include <math.h>

#define Bc 16
#define Nc 4096

typedef __attribute__((ext_vector_type(8))) short short8;
typedef __attribute__((ext_vector_type(4))) float floatx4;

__device__ __forceinline__ unsigned short f2bf(float f) {
    union { float f; unsigned int u; } v; v.f = f;
    unsigned int u = v.u;
    return (unsigned short)((u + 0x7fffu + ((u >> 16) & 1u)) >> 16);
}
__device__ __forceinline__ float bf2f(unsigned short u) {
    union { unsigned int u; float f; } v; v.u = ((unsigned int)u) << 16;
    return v.f;
}

// branch-free gelu: erf via Abramowitz-Stegun 7.1.26 (|err|<=1.5e-7)
// validated rounds 2-7: absmax identical to libm erff path
__device__ __forceinline__ float gelu_f(float x) {
    const float z = x * 0.70710678118654752f;
    const float az = fabsf(z);
    const float t = 1.f / (1.f + 0.3275911f * az);
    const float poly = t * (0.254829592f + t * (-0.284496736f +
                       t * (1.421413741f + t * (-1.453152027f + t * 1.061405429f))));
    const float e = __expf(-z * z);
    const float er = copysignf(1.f - poly * e, z);
    return 0.5f * x * (1.f + er);
}

// async global->LDS 16B/lane; LDS dest must be wave-uniform base + lane*16
__device__ __forceinline__ void gll16(const unsigned short* g, unsigned short* l) {
    __builtin_amdgcn_global_load_lds(
        (const __attribute__((address_space(1))) void*)g,
        (__attribute__((address_space(3))) void*)l,
        16, 0, 0);
}

// ---------------------------------------------------------------------------
// Swapped-operand bf16 GEMM, 512 threads, tile 128(M)x256(N), BK=64.
// Single-buffered LDS 48KB (verified-best; dbuf/small-tile/reg-pipeline and
// in-GEMM LN fusion all regressed -- ledger r0 vs r1/r3/r7).
// XOR-granule LDS swizzle (bank-conflict-free, gll16-compatible).
// EPI 1: + column sum-of-squares -> norm2        (G2)
// EPI 2: A staged with scale -Pi*attn, attn computed inline from S,T (G3)
// EPI 3: + bf16 residual, fp32 out (A via gll16) (G5)
// EPI 4: + per-row sum/sumsq -> rowstats         (G4)
// ---------------------------------------------------------------------------
template <int EPI, typename TOUT>
__global__ __launch_bounds__(512) void gemm_bf(
    const unsigned short* __restrict__ A0, int lda0,
    const unsigned short* __restrict__ A1, int lda1, int K0,
    const unsigned short* __restrict__ W,
    const float* __restrict__ bias,
    const unsigned short* __restrict__ resid_bf,   // EPI3
    const float* __restrict__ Pi,                  // EPI2
    const float* __restrict__ Sb,                  // EPI2
    const float* __restrict__ Tb,                  // EPI2
    float* __restrict__ norm2,                     // EPI1
    float* __restrict__ rowstats,                  // EPI4 (write)
    TOUT* __restrict__ C, int N, int K)
{
    __shared__ alignas(16) unsigned short As[128 * 64];
    __shared__ alignas(16) unsigned short Bs[256 * 64];

    const int t = threadIdx.x;
    const int bn = blockIdx.x, bm = blockIdx.y;
    const int lane = t & 63, wave = t >> 6;          // 8 waves
    const int wm = wave >> 2, wn = wave & 3;         // 2 x 4
    const int quad = lane >> 4, l16 = lane & 15;
    const int rt = t >> 3, st = t & 7;               // rt 0..63

    floatx4 acc[4][4];
    #pragma unroll
    for (int i = 0; i < 4; ++i)
        #pragma unroll
        for (int j = 0; j < 4; ++j)
            acc[i][j] = (floatx4){0.f, 0.f, 0.f, 0.f};

    for (int k0 = 0; k0 < K; k0 += 64) {
        // A tile: 128 rows x 64
        #pragma unroll
        for (int hh = 0; hh < 2; ++hh) {
            const int row = hh * 64 + rt;
            const int col = k0 + (st ^ (row & 7)) * 8;
            unsigned short* ldsa = As + row * 64 + st * 8;
            const size_t grow = (size_t)bm * 128 + row;
            if constexpr (EPI == 2) {
                const int b = (int)(grow >> 12);
                const int hd = col >> 6;
                const float Sv = Sb[b * 4 + hd], Tv = Tb[b * 4 + hd];
                const float at = 1.f / (1.f + Tv / (Sv + 1e-8f));
                const float sc = -Pi[grow * 4 + hd] * at;
                const short8 a = *(const short8*)(A0 + grow * (size_t)lda0 + col);
                short8 o;
                #pragma unroll
                for (int j = 0; j < 8; ++j) o[j] = (short)f2bf(bf2f((unsigned short)a[j]) * sc);
                *(short8*)ldsa = o;
            } else {
                const unsigned short* src = (col < K0)
                    ? (A0 + grow * (size_t)lda0 + col)
                    : (A1 + grow * (size_t)lda1 + (col - K0));
                gll16(src, ldsa);
            }
        }
        // W tile: 256 rows x 64
        #pragma unroll
        for (int hh = 0; hh < 4; ++hh) {
            const int row = hh * 64 + rt;
            const int col = k0 + (st ^ (row & 7)) * 8;
            gll16(W + ((size_t)bn * 256 + row) * (size_t)K + col, Bs + row * 64 + st * 8);
        }
        __syncthreads();
        #pragma unroll
        for (int kk = 0; kk < 2; ++kk) {
            short8 af[4], wf[4];
            #pragma unroll
            for (int i = 0; i < 4; ++i) {
                const int ra = wm * 64 + i * 16 + l16;
                af[i] = *(const short8*)(As + ra * 64 + ((quad + kk * 4) ^ (ra & 7)) * 8);
                const int rw = wn * 64 + i * 16 + l16;
                wf[i] = *(const short8*)(Bs + rw * 64 + ((quad + kk * 4) ^ (rw & 7)) * 8);
            }
            #pragma unroll
            for (int mi = 0; mi < 4; ++mi)
                #pragma unroll
                for (int ni = 0; ni < 4; ++ni)
                    acc[mi][ni] = __builtin_amdgcn_mfma_f32_16x16x32_bf16(
                        wf[ni], af[mi], acc[mi][ni], 0, 0, 0);
        }
        __syncthreads();
    }

    // epilogue: row = bm*128+wm*64+mi*16+l16; col = bn*256+wn*64+ni*16+quad*4+rg
    float rs[4], rq[4];
    if constexpr (EPI == 4) {
        #pragma unroll
        for (int m = 0; m < 4; ++m) { rs[m] = 0.f; rq[m] = 0.f; }
    }

    #pragma unroll
    for (int mi = 0; mi < 4; ++mi) {
        const size_t row = (size_t)bm * 128 + wm * 64 + mi * 16 + l16;
        #pragma unroll
        for (int ni = 0; ni < 4; ++ni) {
            const int cb = bn * 256 + wn * 64 + ni * 16 + quad * 4;
            const float4 b4 = *(const float4*)(bias + cb);
            float v[4] = {acc[mi][ni][0] + b4.x, acc[mi][ni][1] + b4.y,
                          acc[mi][ni][2] + b4.z, acc[mi][ni][3] + b4.w};
            if constexpr (EPI == 3) {
                const ushort4 xr = *(const ushort4*)(resid_bf + row * (size_t)N + cb);
                v[0] += bf2f(xr.x); v[1] += bf2f(xr.y);
                v[2] += bf2f(xr.z); v[3] += bf2f(xr.w);
            }
            if constexpr (EPI == 4) {
                #pragma unroll
                for (int rg = 0; rg < 4; ++rg) { rs[mi] += v[rg]; rq[mi] += v[rg] * v[rg]; }
            }
            if constexpr (EPI == 1) {
                float cs[4];
                #pragma unroll
                for (int rg = 0; rg < 4; ++rg) cs[rg] = v[rg] * v[rg];
                #pragma unroll
                for (int rg = 0; rg < 4; ++rg) {
                    float s = cs[rg];
                    s += __shfl_xor(s, 1, 64);
                    s += __shfl_xor(s, 2, 64);
                    s += __shfl_xor(s, 4, 64);
                    s += __shfl_xor(s, 8, 64);
                    if (l16 == 0) atomicAdd(&norm2[(bm >> 5) * 256 + cb + rg], s);
                }
            }
            if constexpr (__is_same(TOUT, float)) {
                float4 o; o.x = v[0]; o.y = v[1]; o.z = v[2]; o.w = v[3];
                *(float4*)(C + row * (size_t)N + cb) = o;
            } else {
                ushort4 o;
                o.x = f2bf(v[0]); o.y = f2bf(v[1]); o.z = f2bf(v[2]); o.w = f2bf(v[3]);
                *(ushort4*)(C + row * (size_t)N + cb) = o;
            }
        }
    }
    if constexpr (EPI == 4) {
        #pragma unroll
        for (int mi = 0; mi < 4; ++mi) {
            float s = rs[mi], q = rq[mi];
            s += __shfl_xor(s, 16, 64); s += __shfl_xor(s, 32, 64);
            q += __shfl_xor(q, 16, 64); q += __shfl_xor(q, 32, 64);
            if (quad == 0) {
                const size_t row = (size_t)bm * 128 + wm * 64 + mi * 16 + l16;
                atomicAdd(&rowstats[row * 2], s);
                atomicAdd(&rowstats[row * 2 + 1], q);
            }
        }
    }
}

// ---------------------------------------------------------------------------
// G1 (swapped, 256 threads, 128x128 tile, BK=64): dual-acc s/v GEMM with
// in-lane rope epilogue. wi = ((q+k)*e0 + rot(q+k)*e1 + v)/3.  (r0-verified)
// ---------------------------------------------------------------------------
__global__ __launch_bounds__(256) void gemm_rope(
    const unsigned short* __restrict__ A,    // x_bf
    const unsigned short* __restrict__ Wsv,  // 512x256: rows 0-255 s, 256-511 v
    const float* __restrict__ bsv,           // 512
    const float* __restrict__ enc,
    unsigned short* __restrict__ wi)
{
    __shared__ alignas(16) unsigned short As[128 * 64];
    __shared__ alignas(16) unsigned short Ss[128 * 64];
    __shared__ alignas(16) unsigned short Vs[128 * 64];

    const int t = threadIdx.x;
    const int bn = blockIdx.x, bm = blockIdx.y;
    const int lane = t & 63, wave = t >> 6;
    const int wm = wave >> 1, wn = wave & 1;
    const int quad = lane >> 4, l16 = lane & 15;
    const int rt = t >> 3, st = t & 7;   // rt 0..31

    floatx4 accs[4][4], accv[4][4];
    #pragma unroll
    for (int i = 0; i < 4; ++i)
        #pragma unroll
        for (int j = 0; j < 4; ++j) {
            accs[i][j] = (floatx4){0.f, 0.f, 0.f, 0.f};
            accv[i][j] = (floatx4){0.f, 0.f, 0.f, 0.f};
        }

    for (int k0 = 0; k0 < 256; k0 += 64) {
        #pragma unroll
        for (int hh = 0; hh < 4; ++hh) {
            const int row = hh * 32 + rt;
            const int col = k0 + (st ^ (row & 7)) * 8;
            gll16(A + ((size_t)bm * 128 + row) * 256 + col, As + row * 64 + st * 8);
            gll16(Wsv + (size_t)(bn * 128 + row) * 256 + col, Ss + row * 64 + st * 8);
            gll16(Wsv + (size_t)(256 + bn * 128 + row) * 256 + col, Vs + row * 64 + st * 8);
        }
        __syncthreads();
        #pragma unroll
        for (int kk = 0; kk < 2; ++kk) {
            short8 af[4], sf[4], vf[4];
            #pragma unroll
            for (int i = 0; i < 4; ++i) {
                const int ra = wm * 64 + i * 16 + l16;
                af[i] = *(const short8*)(As + ra * 64 + ((quad + kk * 4) ^ (ra & 7)) * 8);
                const int rw = wn * 64 + i * 16 + l16;
                sf[i] = *(const short8*)(Ss + rw * 64 + ((quad + kk * 4) ^ (rw & 7)) * 8);
                vf[i] = *(const short8*)(Vs + rw * 64 + ((quad + kk * 4) ^ (rw & 7)) * 8);
            }
            #pragma unroll
            for (int mi = 0; mi < 4; ++mi)
                #pragma unroll
                for (int ni = 0; ni < 4; ++ni) {
                    accs[mi][ni] = __builtin_amdgcn_mfma_f32_16x16x32_bf16(sf[ni], af[mi], accs[mi][ni], 0, 0, 0);
                    accv[mi][ni] = __builtin_amdgcn_mfma_f32_16x16x32_bf16(vf[ni], af[mi], accv[mi][ni], 0, 0, 0);
                }
        }
        __syncthreads();
    }

    // epilogue: row = bm*128+wm*64+mi*16+l16; cols cb..cb+3 (pairs in-lane)
    #pragma unroll
    for (int mi = 0; mi < 4; ++mi) {
        const size_t row = (size_t)bm * 128 + wm * 64 + mi * 16 + l16;
        #pragma unroll
        for (int ni = 0; ni < 4; ++ni) {
            const int cb = bn * 128 + wn * 64 + ni * 16 + quad * 4;
            const int d = cb & 63;
            const float s0 = accs[mi][ni][0] + bsv[cb];
            const float s1 = accs[mi][ni][1] + bsv[cb + 1];
            const float s2 = accs[mi][ni][2] + bsv[cb + 2];
            const float s3 = accs[mi][ni][3] + bsv[cb + 3];
            const float v0 = accv[mi][ni][0] + bsv[256 + cb];
            const float v1 = accv[mi][ni][1] + bsv[256 + cb + 1];
            const float v2 = accv[mi][ni][2] + bsv[256 + cb + 2];
            const float v3 = accv[mi][ni][3] + bsv[256 + cb + 3];
            const float4 e0q = *(const float4*)(enc + row * 64 + d);
            const float4 e1q = *(const float4*)(enc + 4194304 + row * 64 + d);
            const float r0 = s0 * e0q.x - s1 * e1q.x;
            const float r1 = s1 * e0q.y + s0 * e1q.y;
            const float r2 = s2 * e0q.z - s3 * e1q.z;
            const float r3 = s3 * e0q.w + s2 * e1q.w;
            ushort4 o;
            o.x = f2bf((r0 + v0) * (1.f / 3.f));
            o.y = f2bf((r1 + v1) * (1.f / 3.f));
            o.z = f2bf((r2 + v2) * (1.f / 3.f));
            o.w = f2bf((r3 + v3) * (1.f / 3.f));
            *(ushort4*)(wi + row * 256 + cb) = o;
        }
    }
}

// ---------------------------------------------------------------------------
// LN(512)+gelu_f streaming pass using precomputed rowstats (no reduction).
// Split-path validated faster than in-GEMM fusion (r0 vs r1/r3/r7 ledger);
// gelu_f replaces r0's erff (~18 VALU ops vs ~91).
// ---------------------------------------------------------------------------
__global__ __launch_bounds__(256) void lngelu_kernel(unsigned short* __restrict__ h1,
                                                     const float* __restrict__ rowstats,
                                                     const float* __restrict__ g,
                                                     const float* __restrict__ bb) {
    const size_t gid = (size_t)blockIdx.x * 256 + threadIdx.x;
    const size_t row = gid >> 6;
    const int col = (int)(gid & 63) * 8;
    const float2 stv = *(const float2*)(rowstats + row * 2);
    const float mean = stv.x * (1.f / 512.f);
    const float var = stv.y * (1.f / 512.f) - mean * mean;
    const float rstd = rsqrtf(var + 1e-5f);
    unsigned short* p = h1 + row * 512 + col;
    const short8 hv = *(const short8*)p;
    const float4 g0 = *(const float4*)(g + col);
    const float4 g1 = *(const float4*)(g + col + 4);
    const float4 b0 = *(const float4*)(bb + col);
    const float4 b1 = *(const float4*)(bb + col + 4);
    const float vg[8] = {g0.x, g0.y, g0.z, g0.w, g1.x, g1.y, g1.z, g1.w};
    const float vb[8] = {b0.x, b0.y, b0.z, b0.w, b1.x, b1.y, b1.z, b1.w};
    short8 ov;
    #pragma unroll
    for (int k = 0; k < 8; ++k) {
        const float ln = (bf2f((unsigned short)hv[k]) - mean) * rstd * vg[k] + vb[k];
        ov[k] = (short)f2bf(gelu_f(ln));
    }
    *(short8*)p = ov;
}

// ---------------------------------------------------------------------------
// single prep kernel: converts + fused weights + zeroing
// ---------------------------------------------------------------------------
__device__ __forceinline__ void conv8(const float* src, unsigned short* dst, int i) {
    const float4 f0 = *(const float4*)(src + (size_t)i * 8);
    const float4 f1 = *(const float4*)(src + (size_t)i * 8 + 4);
    short8 sv;
    sv[0] = (short)f2bf(f0.x); sv[1] = (short)f2bf(f0.y);
    sv[2] = (short)f2bf(f0.z); sv[3] = (short)f2bf(f0.w);
    sv[4] = (short)f2bf(f1.x); sv[5] = (short)f2bf(f1.y);
    sv[6] = (short)f2bf(f1.z); sv[7] = (short)f2bf(f1.w);
    *(short8*)(dst + (size_t)i * 8) = sv;
}

__global__ __launch_bounds__(256) void prep_all(
    const float* __restrict__ x, const float* __restrict__ Wqkv,
    const float* __restrict__ bqkv, const float* __restrict__ tssa_w,
    const float* __restrict__ op_w, const float* __restrict__ to_w,
    const float* __restrict__ to_b, const float* __restrict__ op_b,
    const float* __restrict__ f1w, const float* __restrict__ f2w,
    unsigned short* __restrict__ x_bf, unsigned short* __restrict__ Wsv,
    float* __restrict__ bsv, unsigned short* __restrict__ tssa_bf,
    unsigned short* __restrict__ Wf, float* __restrict__ bfb,
    unsigned short* __restrict__ ffn1_bf, unsigned short* __restrict__ ffn2_bf,
    float* __restrict__ zbase, float* __restrict__ rowstats)
{
    const int blk = blockIdx.x, tt = threadIdx.x;
    if (blk < 8192) {
        conv8(x, x_bf, blk * 256 + tt);
    } else if (blk < 8704) {
        const int r = blk - 8192, c = tt;
        const int cd = r & 255;
        const int h = cd >> 6, dd = cd & 63;
        const int base = h * 192 + dd * 3;
        if (r < 256) {
            Wsv[r * 256 + c] = f2bf(Wqkv[(base + 0) * 256 + c] + Wqkv[(base + 1) * 256 + c]);
            if (c == 0) bsv[r] = bqkv[base] + bqkv[base + 1];
        } else {
            Wsv[r * 256 + c] = f2bf(Wqkv[(base + 2) * 256 + c]);
            if (c == 0) bsv[r] = bqkv[base + 2];
        }
    } else if (blk < 8960) {
        const int i = blk - 8704;
        float s = 0.f;
        for (int k = 0; k < 256; ++k) s += op_w[i * 256 + k] * to_w[k * 256 + tt];
        Wf[i * 256 + tt] = f2bf(s);
    } else if (blk == 8960) {
        float s = op_b[tt];
        for (int k = 0; k < 256; ++k) s += op_w[tt * 256 + k] * to_b[k];
        bfb[tt] = s;
    } else if (blk < 8993) {
        conv8(tssa_w, tssa_bf, (blk - 8961) * 256 + tt);
    } else if (blk < 9121) {
        conv8(f1w, ffn1_bf, (blk - 8993) * 256 + tt);
    } else if (blk < 9185) {
        conv8(f2w, ffn2_bf, (blk - 9121) * 256 + tt);
    } else {
        const int i = (blk - 9185) * 256 + tt;
        if (i < 4288) zbase[i] = 0.f;
        else if (i < 135360) rowstats[i - 4288] = 0.f;
    }
}

// ---------------------------------------------------------------------------
// per-row softmax over heads + S/T accumulation
// ---------------------------------------------------------------------------
__global__ __launch_bounds__(256) void pi_kernel(const unsigned short* __restrict__ w,
                                                 const float* __restrict__ norm2,
                                                 const float* __restrict__ temp,
                                                 float* __restrict__ Pi,
                                                 float* __restrict__ S,
                                                 float* __restrict__ T) {
    const int t = threadIdx.x;
    const int i = t & 15;
    const int lr = t >> 4;
    const size_t r = (size_t)blockIdx.x * 16 + lr;
    const int b = (int)(r >> 12);
    const unsigned short* wrow = w + r * 256;
    const float* n2row = norm2 + b * 256;
    float raw[4], nrm[4];
    #pragma unroll
    for (int h = 0; h < 4; ++h) {
        const ushort4 wv = *(const ushort4*)(wrow + h * 64 + i * 4);
        const float w0 = bf2f(wv.x), w1 = bf2f(wv.y), w2 = bf2f(wv.z), w3 = bf2f(wv.w);
        const float4 n2 = *(const float4*)(n2row + h * 64 + i * 4);
        const float s0 = w0 * w0, s1 = w1 * w1, s2 = w2 * w2, s3 = w3 * w3;
        raw[h] = s0 + s1 + s2 + s3;
        nrm[h] = s0 / fmaxf(n2.x, 1e-24f) + s1 / fmaxf(n2.y, 1e-24f)
               + s2 / fmaxf(n2.z, 1e-24f) + s3 / fmaxf(n2.w, 1e-24f);
    }
    #pragma unroll
    for (int off = 1; off < 16; off <<= 1) {
        #pragma unroll
        for (int h = 0; h < 4; ++h) {
            raw[h] += __shfl_xor(raw[h], off, 64);
            nrm[h] += __shfl_xor(nrm[h], off, 64);
        }
    }
    float sw[4], m = -1e30f;
    #pragma unroll
    for (int h = 0; h < 4; ++h) { sw[h] = nrm[h] * temp[h]; m = fmaxf(m, sw[h]); }
    float e[4], Z = 0.f;
    #pragma unroll
    for (int h = 0; h < 4; ++h) { e[h] = expf(sw[h] - m); Z += e[h]; }
    const float invZ = 1.f / Z;
    float pi[4];
    #pragma unroll
    for (int h = 0; h < 4; ++h) pi[h] = e[h] * invZ;
    if (i < 4) Pi[r * 4 + i] = pi[i];

    __shared__ float sS[16][4], sT[16][4];
    if (i == 0) {
        #pragma unroll
        for (int h = 0; h < 4; ++h) { sS[lr][h] = pi[h]; sT[lr][h] = pi[h] * raw[h]; }
    }
    __syncthreads();
    if (t < 4) {
        float as = 0.f, at = 0.f;
        for (int rr = 0; rr < 16; ++rr) { as += sS[rr][t]; at += sT[rr][t]; }
        atomicAdd(&S[b * 4 + t], as);
        atomicAdd(&T[b * 4 + t], at);
    }
}

// ---------------------------------------------------------------------------
extern "C" void kernel_launch(void* const* d_in, const int* in_sizes, int n_in,
                              void* d_out, int out_size, void* d_ws, size_t ws_size,
                              hipStream_t stream) {
    (void)in_sizes; (void)n_in; (void)out_size; (void)ws_size;
    const float* x          = (const float*)d_in[0];
    const float* enc        = (const float*)d_in[1];
    const float* Wqkv_w     = (const float*)d_in[2];
    const float* Wqkv_b     = (const float*)d_in[3];
    const float* tssa_qkv_w = (const float*)d_in[4];
    const float* tssa_qkv_b = (const float*)d_in[5];
    const float* temp       = (const float*)d_in[6];
    const float* tssa_out_w = (const float*)d_in[7];
    const float* tssa_out_b = (const float*)d_in[8];
    const float* out_proj_w = (const float*)d_in[9];
    const float* out_proj_b = (const float*)d_in[10];
    const float* ffn1_w     = (const float*)d_in[11];
    const float* ffn1_b     = (const float*)d_in[12];
    const float* ln_g       = (const float*)d_in[13];
    const float* ln_b       = (const float*)d_in[14];
    const float* ffn2_w     = (const float*)d_in[15];
    const float* ffn2_b     = (const float*)d_in[16];
    float* outp = (float*)d_out;

    const int M = Bc * Nc;  // 65536

    char* ws = (char*)d_ws;
    unsigned short* x_bf  = (unsigned short*)(ws);
    unsigned short* wi_bf = (unsigned short*)(ws + (size_t)(32 << 20));
    unsigned short* h1_bf = (unsigned short*)(ws + (size_t)(32 << 20));
    unsigned short* w_bf  = (unsigned short*)(ws + (size_t)(64 << 20));
    unsigned short* msg_bf= (unsigned short*)(ws + (size_t)(96 << 20));
    float* fb    = (float*)(ws + (size_t)(128 << 20));
    float* Pi    = fb;                 // 262144
    float* norm2 = Pi + 262144;        // 4096  <- zero base
    float* Sb    = norm2 + 4096;       // 64
    float* Tb    = Sb + 64;            // 64
    float* attnb = Tb + 64;            // 64 (unused, kept for zero-range layout)
    float* bsv   = attnb + 64;         // 512
    float* bfb   = bsv + 512;          // 256
    float* rowstats = bfb + 256;       // 131072
    unsigned short* Wsv_bf  = (unsigned short*)(rowstats + 131072);
    unsigned short* tssa_bf = Wsv_bf + 131072;
    unsigned short* Wf_bf   = tssa_bf + 65536;
    unsigned short* ffn1_bf = Wf_bf + 65536;
    unsigned short* ffn2_bf = ffn1_bf + 262144;

    // 1. prep
    prep_all<<<9714, 256, 0, stream>>>(
        x, Wqkv_w, Wqkv_b, tssa_qkv_w, out_proj_w, tssa_out_w, tssa_out_b,
        out_proj_b, ffn1_w, ffn2_w,
        x_bf, Wsv_bf, bsv, tssa_bf, Wf_bf, bfb, ffn1_bf, ffn2_bf,
        norm2, rowstats);

    // 2. G1: wi = rope-combine(x_bf @ [Wqk;Wv]^T + b)
    gemm_rope<<<dim3(2, M / 128), 256, 0, stream>>>(x_bf, Wsv_bf, bsv, enc, wi_bf);

    // 3. G2: w = wi @ tssa^T + b -> bf16, fused colsq -> norm2
    gemm_bf<1, unsigned short><<<dim3(1, M / 128), 512, 0, stream>>>(
        wi_bf, 256, wi_bf, 256, 256, tssa_bf, tssa_qkv_b,
        nullptr, nullptr, nullptr, nullptr, norm2, nullptr,
        w_bf, 256, 256);

    // 4. stats (attn folded into G3's staging)
    pi_kernel<<<4096, 256, 0, stream>>>(w_bf, norm2, temp, Pi, Sb, Tb);

    // 5. G3: message = (-w*Pi*attn) @ Wf^T + bfb, attn = 1/(1+T/(S+eps)) inline
    gemm_bf<2, unsigned short><<<dim3(1, M / 128), 512, 0, stream>>>(
        w_bf, 256, w_bf, 256, 256, Wf_bf, bfb,
        nullptr, Pi, Sb, Tb, nullptr, nullptr,
        msg_bf, 256, 256);

    // 6. G4: h1 = [x_bf, msg] @ ffn1^T + b -> bf16, fused row sum/sumsq
    gemm_bf<4, unsigned short><<<dim3(2, M / 128), 512, 0, stream>>>(
        x_bf, 256, msg_bf, 256, 256, ffn1_bf, ffn1_b,
        nullptr, nullptr, nullptr, nullptr, nullptr, rowstats,
        h1_bf, 512, 512);

    // 7. LN+gelu streaming (rowstats precomputed; gelu_f)
    lngelu_kernel<<<16384, 256, 0, stream>>>(h1_bf, rowstats, ln_g, ln_b);

    // 8. G5: out = x + gelu'd(h1) @ ffn2^T + b (fp32 out, bf16 residual)
    gemm_bf<3, float><<<dim3(1, M / 128), 512, 0, stream>>>(
        h1_bf, 512, h1_bf, 512, 512, ffn2_bf, ffn2_b,
        x_bf, nullptr, nullptr, nullptr, nullptr, nullptr,
        outp, 256, 512);
}